// Round 4
// baseline (139.808 us; speedup 1.0000x reference)
//
#include <hip/hip_runtime.h>
#include <math.h>

// ConsistencyLoss: KL( softmax(soft/T) || softmax(logits/T) ) * T^2, batchmean.
// B = 4,194,304, C = 5, T = 3.
//
// R10 = R9 resubmitted verbatim (R9's bench was an infra failure: container
// acquisition died twice; no counters came back). Audit found no OOB, no
// divergent barriers, vmcnt group arithmetic exact -> kernel is sound.
//
// R9 theory: pipeline the stream. Headline pinned at ~136us across 3
// structurally different kernels; top-5 dispatches are all 51us/320MB poison
// fills -> partial kernel <51us, decomposing to ~30us vs a ~16us HBM floor.
// R8's wave did {issue 6 loads -> vmcnt(0) -> full ~900cy latency stall ->
// compute -> exit}: latency + compute in SERIES for every block = ~1/2 BW.
// Now: persistent blocks (1024 = exactly 4/CU at 40KB LDS, fully resident),
// 4 tiles/block, per-wave private DOUBLE-buffered 5KB staging, counted
// s_waitcnt vmcnt(6) (T4: wait only for the PREVIOUS tile's 6 loads, never
// drain to 0 in the loop) -> HBM latency hides under the ~800cy compute of
// the other buffer. wsum aliased into sbuf (LDS stays exactly 40960B for
// 4 blocks/CU); a barrier before the aliased use drains all staging writes.

constexpr int   kC     = 5;
constexpr float kInvT  = 1.0f / 3.0f;
constexpr float kExp13 = 1.3956124250860895f;   // e^{1/3}
constexpr int   kBatch = 4194304;

constexpr int kThreads       = 256;                  // 4 waves
constexpr int kQuadsPerTile  = kThreads;             // 1 quad/thread/tile
constexpr int kTilesPerBlock = 4;
constexpr int kBlocks = (kBatch / 4) / (kQuadsPerTile * kTilesPerBlock); // 1024

__device__ __forceinline__ float kl_quad(float4 P0, float4 P1, float4 P2,
                                         float4 P3, float4 P4, float4 s4) {
    const float v[20] = {P0.x, P0.y, P0.z, P0.w,
                         P1.x, P1.y, P1.z, P1.w,
                         P2.x, P2.y, P2.z, P2.w,
                         P3.x, P3.y, P3.z, P3.w,
                         P4.x, P4.y, P4.z, P4.w};
    const float ss[4] = {s4.x, s4.y, s4.z, s4.w};

    float acc = 0.0f;
    #pragma unroll
    for (int r = 0; r < 4; ++r) {
        const float s  = ss[r];
        const float l0 = v[r * 5 + 0], l1 = v[r * 5 + 1], l2 = v[r * 5 + 2],
                    l3 = v[r * 5 + 3], l4 = v[r * 5 + 4];

        // --- soft target geometry (matches reference exactly) ---
        const float sc     = fminf(fmaxf(s * 5.0f, 0.0f), 4.0f);
        const int   idx    = (int)sc;                    // floor, s >= 0
        const float center = ((float)idx + 0.5f) * 0.2f;
        float       d      = fabsf(s - center) * 5.0f;
        const bool  lo     = (idx > 0) && (s < center);
        const bool  hi     = (idx < kC - 1) && (s > center);
        const bool  nb     = lo || hi;
        d = nb ? d : 0.0f;
        const int nbi = idx + (hi ? 1 : 0) - (lo ? 1 : 0);

        // soft = {1-d at idx, d at nbi, 0 elsewhere};  e_main = e^{1/3}/e_nb
        const float e_nb   = __expf(d * kInvT);
        const float e_main = kExp13 * __builtin_amdgcn_rcpf(e_nb);

        const float S = l0 + l1 + l2 + l3 + l4;
        const float l_main = (idx == 0) ? l0 : (idx == 1) ? l1 :
                             (idx == 2) ? l2 : (idx == 3) ? l3 : l4;
        const float l_nb   = (nbi == 0) ? l0 : (nbi == 1) ? l1 :
                             (nbi == 2) ? l2 : (nbi == 3) ? l3 : l4;

        const float Zq = __expf(l0 * kInvT) + __expf(l1 * kInvT) +
                         __expf(l2 * kInvT) + __expf(l3 * kInvT) +
                         __expf(l4 * kInvT);

        const float Zp  = e_main + e_nb + 3.0f;
        const float rZp = __builtin_amdgcn_rcpf(Zp);
        const float Spa = e_main * (1.0f - d) + e_nb * d;
        const float Spl = e_main * l_main + e_nb * l_nb + (S - l_main - l_nb);

        acc += kInvT * (Spa - Spl) * rZp + __logf(Zq * rZp);
    }
    return acc;
}

__global__ __launch_bounds__(kThreads) void kl_partial_kernel(
    const float* __restrict__ score,
    const float* __restrict__ logits,
    float* __restrict__ partial) {

    // [buf][wave][float4]: 2 x 4 x 320 x 16B = 40960 B exactly -> 4 blocks/CU.
    __shared__ float4 sbuf[2][4][320];

    const int t    = threadIdx.x;
    const int wave = t >> 6;                     // 0..3
    const int lane = t & 63;

    const float4* __restrict__ glog = reinterpret_cast<const float4*>(logits);
    const float4* __restrict__ gsc  = reinterpret_cast<const float4*>(score);
    const size_t tile0 = (size_t)blockIdx.x * kTilesPerBlock;

    // STAGE tile tt into buffer b: 5 x global_load_lds width=16 (wave-uniform
    // LDS base + lane*16, contiguous 1KB/instr) + this thread's score float4.
    // 6 vmem ops per stage group; groups can't split across the asm waits
    // ("memory" clobber pins loads on both sides).
    auto stage = [&](int tt, int b) -> float4 {
        const size_t q0 = (tile0 + tt) * kQuadsPerTile;
        const float4* src = glog + q0 * 5 + wave * 320;
        #pragma unroll
        for (int j = 0; j < 5; ++j) {
            __builtin_amdgcn_global_load_lds(
                (const __attribute__((address_space(1))) void*)(src + j * 64 + lane),
                (__attribute__((address_space(3))) void*)(&sbuf[b][wave][j * 64]),
                16, 0, 0);
        }
        return gsc[q0 + t];
    };
    // Consume buffer b (stride-5 float4: each 8-lane group covers all 32
    // banks once -> conflict-free ds_read_b128).
    auto consume = [&](int b, float4 s4) -> float {
        const int a0 = lane * 5;
        return kl_quad(sbuf[b][wave][a0], sbuf[b][wave][a0 + 1],
                       sbuf[b][wave][a0 + 2], sbuf[b][wave][a0 + 3],
                       sbuf[b][wave][a0 + 4], s4);
    };

    // 2-deep pipeline over 4 tiles; vmcnt(6) waits only for the previous
    // tile's 6 loads (6 newer remain in flight). Static buffer indices only.
    float acc = 0.0f;
    float4 s0 = stage(0, 0);
    float4 s1 = stage(1, 1);
    asm volatile("s_waitcnt vmcnt(6)" ::: "memory");   // tile0 landed
    acc += consume(0, s0);
    s0 = stage(2, 0);
    asm volatile("s_waitcnt vmcnt(6)" ::: "memory");   // tile1 landed
    acc += consume(1, s1);
    s1 = stage(3, 1);
    asm volatile("s_waitcnt vmcnt(6)" ::: "memory");   // tile2 landed
    acc += consume(0, s0);
    asm volatile("s_waitcnt vmcnt(0)" ::: "memory");   // tile3 landed (epilogue)
    acc += consume(1, s1);

    // --- wave (64-lane) shuffle reduction ---
    #pragma unroll
    for (int off = 32; off > 0; off >>= 1) acc += __shfl_down(acc, off, 64);

    // wsum aliased into sbuf to keep LDS at exactly 40960B. The barrier's
    // implicit vmcnt(0) per wave guarantees ALL waves' staging writes have
    // landed before any wsum write touches the aliased bytes.
    __syncthreads();
    float* wsum = reinterpret_cast<float*>(&sbuf[0][0][0]);
    if (lane == 0) wsum[wave] = acc;
    __syncthreads();
    if (t == 0) {
        partial[blockIdx.x] = wsum[0] + wsum[1] + wsum[2] + wsum[3];
    }
}

__global__ __launch_bounds__(256) void kl_final_kernel(
    const float* __restrict__ partial,
    float* __restrict__ out) {
    const int t = threadIdx.x;
    // 1024 partials = 256 float4s; thread t sums float4 t
    const float4* p4 = reinterpret_cast<const float4*>(partial);
    const float4 a = p4[t];
    float acc = a.x + a.y + a.z + a.w;

    #pragma unroll
    for (int off = 32; off > 0; off >>= 1) acc += __shfl_down(acc, off, 64);

    __shared__ float wsum[4];
    if ((t & 63) == 0) wsum[t >> 6] = acc;
    __syncthreads();
    if (t == 0) {
        out[0] = (wsum[0] + wsum[1] + wsum[2] + wsum[3]) * (9.0f / (float)kBatch);
    }
}

extern "C" void kernel_launch(void* const* d_in, const int* in_sizes, int n_in,
                              void* d_out, int out_size, void* d_ws, size_t ws_size,
                              hipStream_t stream) {
    const float* score  = (const float*)d_in[0];   // quality_score [B]
    const float* logits = (const float*)d_in[1];   // class_logits [B,5]
    float* out     = (float*)d_out;
    float* partial = (float*)d_ws;                 // kBlocks floats, rewritten every call

    kl_partial_kernel<<<kBlocks, kThreads, 0, stream>>>(score, logits, partial);
    kl_final_kernel<<<1, 256, 0, stream>>>(partial, out);
}

// Round 5
// 135.185 us; speedup vs baseline: 1.0342x; 1.0342x over previous
//
#include <hip/hip_runtime.h>
#include <math.h>

// ConsistencyLoss: KL( softmax(soft/T) || softmax(logits/T) ) * T^2, batchmean.
// B = 4,194,304, C = 5, T = 3.
//
// R11: union of the two best measured structures, drop the failed pipeline.
// Evidence from R10 counters: persistent 1024-block pipelined version ran at
// 68.5us with OccupancyPercent=27% and -- decisive -- L3-resident replays
// (FETCH~0) STILL took 68.5us => pure exposed latency from the serial 4-tile
// chain + low occupancy. Lesson: for a zero-reuse stream, TLP > pipelining.
// Headline history: R0 (512thr block-DMA) 134.0 < R7 136.0 < R8 136.6 <
// R9 139.8; headline is dominated by ~102us of harness poison fills.
// This round: R0's shape (512 thr, 2048 independent blocks, 40KB staging,
// 32 waves/CU) with R8's fix (wave-private DMA chunks -> wave-local
// s_waitcnt vmcnt(0), NO block-wide drain before compute). wsum aliased
// into slog4 after an end-of-compute barrier to keep LDS at exactly 40960B.

constexpr int   kC     = 5;
constexpr float kInvT  = 1.0f / 3.0f;
constexpr float kExp13 = 1.3956124250860895f;   // e^{1/3}
constexpr int   kBatch = 4194304;

constexpr int kThreads      = 512;                          // 8 waves
constexpr int kQuadsPerTile = 512;                          // 2048 samples/block
constexpr int kTileVec4     = kQuadsPerTile * 5;            // 2560 float4 = 40 KB
constexpr int kBlocks       = (kBatch / 4) / kQuadsPerTile; // 2048

__device__ __forceinline__ float kl_quad(float4 P0, float4 P1, float4 P2,
                                         float4 P3, float4 P4, float4 s4) {
    const float v[20] = {P0.x, P0.y, P0.z, P0.w,
                         P1.x, P1.y, P1.z, P1.w,
                         P2.x, P2.y, P2.z, P2.w,
                         P3.x, P3.y, P3.z, P3.w,
                         P4.x, P4.y, P4.z, P4.w};
    const float ss[4] = {s4.x, s4.y, s4.z, s4.w};

    float acc = 0.0f;
    #pragma unroll
    for (int r = 0; r < 4; ++r) {
        const float s  = ss[r];
        const float l0 = v[r * 5 + 0], l1 = v[r * 5 + 1], l2 = v[r * 5 + 2],
                    l3 = v[r * 5 + 3], l4 = v[r * 5 + 4];

        // --- soft target geometry (matches reference exactly) ---
        const float sc     = fminf(fmaxf(s * 5.0f, 0.0f), 4.0f);
        const int   idx    = (int)sc;                    // floor, s >= 0
        const float center = ((float)idx + 0.5f) * 0.2f;
        float       d      = fabsf(s - center) * 5.0f;
        const bool  lo     = (idx > 0) && (s < center);
        const bool  hi     = (idx < kC - 1) && (s > center);
        const bool  nb     = lo || hi;
        d = nb ? d : 0.0f;
        const int nbi = idx + (hi ? 1 : 0) - (lo ? 1 : 0);

        // soft = {1-d at idx, d at nbi, 0 elsewhere};  e_main = e^{1/3}/e_nb
        const float e_nb   = __expf(d * kInvT);
        const float e_main = kExp13 * __builtin_amdgcn_rcpf(e_nb);

        const float S = l0 + l1 + l2 + l3 + l4;
        const float l_main = (idx == 0) ? l0 : (idx == 1) ? l1 :
                             (idx == 2) ? l2 : (idx == 3) ? l3 : l4;
        const float l_nb   = (nbi == 0) ? l0 : (nbi == 1) ? l1 :
                             (nbi == 2) ? l2 : (nbi == 3) ? l3 : l4;

        const float Zq = __expf(l0 * kInvT) + __expf(l1 * kInvT) +
                         __expf(l2 * kInvT) + __expf(l3 * kInvT) +
                         __expf(l4 * kInvT);

        const float Zp  = e_main + e_nb + 3.0f;
        const float rZp = __builtin_amdgcn_rcpf(Zp);
        const float Spa = e_main * (1.0f - d) + e_nb * d;
        const float Spl = e_main * l_main + e_nb * l_nb + (S - l_main - l_nb);

        acc += kInvT * (Spa - Spl) * rZp + __logf(Zq * rZp);
    }
    return acc;
}

__global__ __launch_bounds__(kThreads) void kl_partial_kernel(
    const float* __restrict__ score,
    const float* __restrict__ logits,
    float* __restrict__ partial) {

    __shared__ float4 slog4[kTileVec4];          // 40960 B exactly

    const int t    = threadIdx.x;
    const int wave = t >> 6;                     // 0..7
    const int lane = t & 63;
    const size_t tile_quad0 = (size_t)blockIdx.x * kQuadsPerTile;

    // --- per-wave coalesced DMA staging: wave w owns float4s [320w, 320w+320).
    // 5 instrs x contiguous 1KB chunks; LDS dst = wave-uniform base + lane*16.
    const float4* gsrc = reinterpret_cast<const float4*>(logits) + tile_quad0 * 5;
    #pragma unroll
    for (int j = 0; j < 5; ++j) {
        const int base = wave * 320 + j * 64;
        __builtin_amdgcn_global_load_lds(
            (const __attribute__((address_space(1))) void*)(gsrc + base + lane),
            (__attribute__((address_space(3))) void*)(&slog4[base]),
            16, 0, 0);
    }

    // score for this thread's quad (coalesced float4, drains with same wait)
    const float4 sA = reinterpret_cast<const float4*>(score)[tile_quad0 + t];

    // Wave-LOCAL wait: thread t (wave w) reads only [5t, 5t+5) which lies in
    // wave w's own staged chunk -> no __syncthreads needed before compute.
    asm volatile("s_waitcnt vmcnt(0)" ::: "memory");

    // stride-5 float4 reads: start bank (20t)%32; each 8-lane group covers
    // all 32 banks once -> conflict-free ds_read_b128.
    const int a0 = t * 5;
    float acc = kl_quad(slog4[a0], slog4[a0 + 1], slog4[a0 + 2],
                        slog4[a0 + 3], slog4[a0 + 4], sA);

    // --- wave (64-lane) shuffle reduction ---
    #pragma unroll
    for (int off = 32; off > 0; off >>= 1) acc += __shfl_down(acc, off, 64);

    // wsum aliased into slog4 (keeps LDS at exactly 40960B -> 4 blocks/CU).
    // Barrier first: every wave has passed its own vmcnt(0) and consumed its
    // LDS reads, so all DMA writes have landed before the aliased stores.
    __syncthreads();
    float* wsum = reinterpret_cast<float*>(&slog4[0]);
    if (lane == 0) wsum[wave] = acc;
    __syncthreads();
    if (t == 0) {
        float b = 0.0f;
        #pragma unroll
        for (int w = 0; w < 8; ++w) b += wsum[w];
        partial[blockIdx.x] = b;
    }
}

__global__ __launch_bounds__(256) void kl_final_kernel(
    const float* __restrict__ partial,
    float* __restrict__ out) {
    const int t = threadIdx.x;
    // 2048 partials = 512 float4s; thread t sums float4 t and t+256
    const float4* p4 = reinterpret_cast<const float4*>(partial);
    const float4 a = p4[t], b = p4[t + 256];
    float acc = a.x + a.y + a.z + a.w + b.x + b.y + b.z + b.w;

    #pragma unroll
    for (int off = 32; off > 0; off >>= 1) acc += __shfl_down(acc, off, 64);

    __shared__ float wsum[4];
    if ((t & 63) == 0) wsum[t >> 6] = acc;
    __syncthreads();
    if (t == 0) {
        out[0] = (wsum[0] + wsum[1] + wsum[2] + wsum[3]) * (9.0f / (float)kBatch);
    }
}

extern "C" void kernel_launch(void* const* d_in, const int* in_sizes, int n_in,
                              void* d_out, int out_size, void* d_ws, size_t ws_size,
                              hipStream_t stream) {
    const float* score  = (const float*)d_in[0];   // quality_score [B]
    const float* logits = (const float*)d_in[1];   // class_logits [B,5]
    float* out     = (float*)d_out;
    float* partial = (float*)d_ws;                 // kBlocks floats, rewritten every call

    kl_partial_kernel<<<kBlocks, kThreads, 0, stream>>>(score, logits, partial);
    kl_final_kernel<<<1, 256, 0, stream>>>(partial, out);
}